// Round 11
// baseline (1477.782 us; speedup 1.0000x reference)
//
#include <hip/hip_runtime.h>

#define BB 32
#define NPTS0 2048
#define KNB 16
#define KC 256   // key-chunk size for two-pass kNN

constexpr int ilog2c(int n){ int l=0; while(n>1){ n>>=1; ++l; } return l; }

static __device__ __forceinline__ float sq3(float a, float b, float c){
  return __fadd_rn(__fadd_rn(__fmul_rn(a,a),__fmul_rn(b,b)),__fmul_rn(c,c));
}

// DPP helpers: templated so dpp_ctrl/row_mask are integer constant expressions.
template<int CTRL, int RM>
static __device__ __forceinline__ float dpp_maxf(float v){
  int s = __builtin_amdgcn_update_dpp(__float_as_int(v), __float_as_int(v), CTRL, RM, 0xF, false);
  return fmaxf(v, __int_as_float(s));
}
template<int CTRL, int RM>
static __device__ __forceinline__ unsigned dpp_minu(unsigned v){
  unsigned s = (unsigned)__builtin_amdgcn_update_dpp((int)v, (int)v, CTRL, RM, 0xF, false);
  return s < v ? s : v;
}

// ---------------- proj body ----------------
static __device__ __forceinline__ void proj_body(const float* __restrict__ x,
    const float* __restrict__ w, const float* __restrict__ bias, float* __restrict__ f0,
    int blk)
{
  int gid = blk*256 + threadIdx.x;
  if (gid >= BB*NPTS0) return;
  float x0 = x[gid*3+0], x1 = x[gid*3+1], x2 = x[gid*3+2];
  #pragma unroll
  for (int o = 0; o < 8; ++o){
    float acc = __fmul_rn(w[o*3+0], x0);
    acc = __fmaf_rn(w[o*3+1], x1, acc);
    acc = __fmaf_rn(w[o*3+2], x2, acc);
    f0[gid*8+o] = __fadd_rn(acc, bias[o]);
  }
}

// ---------------- kNN pass 1 body: NAMED-SCALAR top-16 (registers, no allocas) ------
#define KDECL(I) float th##I = __builtin_inff(); int ti##I = 0;
#define KINS(I,J) if (th##I < th##J){ float tv=th##I; th##I=th##J; th##J=tv; \
                                      int tj=ti##I; ti##I=ti##J; ti##J=tj; }
#define KST(I) pd[base+I] = th##I; pi[base+I] = (unsigned char)ti##I;

static __device__ __forceinline__ void knn_part_body(const float* __restrict__ qpts,
    const float* __restrict__ kpts, int Nq, int Nk, int nkc,
    float* __restrict__ pd, unsigned char* __restrict__ pi,
    int b, int qcb, int kc, float4* kk4)
{
  int tid = threadIdx.x;
  {
    int j = kc*KC + tid;                 // Nk is always a multiple of 256
    float a = kpts[(b*Nk+j)*3+0];
    float c = kpts[(b*Nk+j)*3+1];
    float d = kpts[(b*Nk+j)*3+2];
    kk4[tid] = make_float4(a, c, d, sq3(a,c,d));
  }
  __syncthreads();
  int q = qcb*256 + tid;
  if (q >= Nq) return;
  float qx = qpts[(b*Nq+q)*3+0], qy = qpts[(b*Nq+q)*3+1], qz = qpts[(b*Nq+q)*3+2];
  float qq = sq3(qx,qy,qz);
  KDECL(0) KDECL(1) KDECL(2) KDECL(3) KDECL(4) KDECL(5) KDECL(6) KDECL(7)
  KDECL(8) KDECL(9) KDECL(10) KDECL(11) KDECL(12) KDECL(13) KDECL(14) KDECL(15)
  for (int j=0;j<KC;j++){
    float4 k4 = kk4[j];
    float dot = __fmul_rn(qx,k4.x);
    dot = __fmaf_rn(qy,k4.y,dot);
    dot = __fmaf_rn(qz,k4.z,dot);
    float d = __fadd_rn(__fsub_rn(qq, __fmul_rn(2.0f,dot)), k4.w);
    if (d < th15){                        // strict <: equal dist keeps earlier index
      th15 = d; ti15 = j;
      KINS(15,14) KINS(14,13) KINS(13,12) KINS(12,11) KINS(11,10) KINS(10,9)
      KINS(9,8) KINS(8,7) KINS(7,6) KINS(6,5) KINS(5,4) KINS(4,3) KINS(3,2)
      KINS(2,1) KINS(1,0)
    }
  }
  size_t base = ((size_t)(b*Nq+q)*nkc + kc)*KNB;
  KST(0) KST(1) KST(2) KST(3) KST(4) KST(5) KST(6) KST(7)
  KST(8) KST(9) KST(10) KST(11) KST(12) KST(13) KST(14) KST(15)
}

// ---------------- FPS: 2 waves x 16(or 4) pts/lane, NO vmem in loop -----------------
// Winner indices buffered in LDS (oibuf) and dumped after the loop: the in-loop
// __syncthreads then waits only on lgkmcnt (no global-store vmcnt(0) drain).
// Selection semantics identical to jnp.argmax over exact f32 distances: per-wave
// fmaxf reduce (bit-preserving), descending-T equality match keeps lowest t,
// u32-min reduce -> lowest index, 2-way (max, lowest-index) merge.
#define REP16(M)  M(0) M(1) M(2) M(3) M(4) M(5) M(6) M(7) \
                  M(8) M(9) M(10) M(11) M(12) M(13) M(14) M(15)
#define REP16D(M) M(15) M(14) M(13) M(12) M(11) M(10) M(9) M(8) \
                  M(7) M(6) M(5) M(4) M(3) M(2) M(1) M(0)
#define REP4(M)   M(0) M(1) M(2) M(3)
#define REP4D(M)  M(3) M(2) M(1) M(0)

// tid&127 clamp: waves 2-3 load valid (duplicate) addresses but never contribute.
#define F2_LOAD(T) float px##T, py##T, pz##T, d##T; { int i_=T*128+(tid&127); \
  px##T=P[i_*3+0]; py##T=P[i_*3+1]; pz##T=P[i_*3+2]; \
  float dx_=__fsub_rn(px##T,c0x), dy_=__fsub_rn(py##T,c0y), dz_=__fsub_rn(pz##T,c0z); \
  d##T=sq3(dx_,dy_,dz_); bm=fmaxf(bm,d##T); }
#define F2_MATCH(T) if (d##T == m_w) ci = (unsigned)(T*128 + tid);
#define F2_OWN(T) if ((idx_w>>7) == (unsigned)T){ cx=px##T; cy=py##T; cz=pz##T; }
#define F2_UPD(T) { float dx_=__fsub_rn(px##T,sx), dy_=__fsub_rn(py##T,sy), dz_=__fsub_rn(pz##T,sz); \
  float nd_=sq3(dx_,dy_,dz_); d##T=fminf(d##T,nd_); bm=fmaxf(bm,d##T); }

#define F2_REDUCE \
  { float v=bm; v=dpp_maxf<0x111,0xF>(v); v=dpp_maxf<0x112,0xF>(v); \
    v=dpp_maxf<0x114,0xF>(v); v=dpp_maxf<0x118,0xF>(v); \
    v=dpp_maxf<0x142,0xA>(v); v=dpp_maxf<0x143,0xC>(v); \
    m_w = __int_as_float(__builtin_amdgcn_readlane(__float_as_int(v),63)); }

#define F2_MINRED \
  { ci=dpp_minu<0x111,0xF>(ci); ci=dpp_minu<0x112,0xF>(ci); \
    ci=dpp_minu<0x114,0xF>(ci); ci=dpp_minu<0x118,0xF>(ci); \
    ci=dpp_minu<0x142,0xA>(ci); ci=dpp_minu<0x143,0xC>(ci); \
    idx_w=(unsigned)__builtin_amdgcn_readlane((int)ci,63); }

#define F2_BODY(NPTS, REPF, REPFD) \
  float (*swp)[2][8] = reinterpret_cast<float(*)[2][8]>(smraw);   /* [2][2][8] */ \
  int* oibuf = reinterpret_cast<int*>(smraw + 256); \
  int tid = threadIdx.x; \
  int wid = (tid >> 6) & 1; \
  bool act = tid < 128; \
  const float* P = pts + (size_t)b*NPTS*3; \
  float c0x=P[0], c0y=P[1], c0z=P[2]; \
  float bm=-1.f; \
  REPF(F2_LOAD) \
  if (tid==0) oibuf[0]=0; \
  for (int s=1; s<S; ++s){ \
    int par = s & 1; \
    if (act){ \
      float m_w; unsigned idx_w; \
      F2_REDUCE \
      unsigned ci = 0xFFFFFFFFu; \
      REPFD(F2_MATCH) \
      F2_MINRED \
      if (tid == (int)(idx_w & 127u)){ \
        float cx=px0, cy=py0, cz=pz0; \
        REPF(F2_OWN) \
        float4* wp = (float4*)&swp[par][wid][0]; \
        *wp = make_float4(m_w, __uint_as_float(idx_w), cx, cy); \
        swp[par][wid][4] = cz; \
      } \
    } \
    __syncthreads();          /* lgkm-only: no vmem issued in-loop */ \
    if (act){ \
      float4 q0 = *(const float4*)&swp[par][0][0]; float z0 = swp[par][0][4]; \
      float4 q1 = *(const float4*)&swp[par][1][0]; float z1 = swp[par][1][4]; \
      float mm = q0.x; unsigned mi = __float_as_uint(q0.y); \
      float sx = q0.z, sy = q0.w, sz = z0; \
      if (q1.x > mm || (q1.x == mm && __float_as_uint(q1.y) < mi)){ \
        mm = q1.x; mi = __float_as_uint(q1.y); sx = q1.z; sy = q1.w; sz = z1; } \
      if (tid == 0) oibuf[s] = (int)mi; \
      bm = -1.f; \
      REPF(F2_UPD) \
    } \
  } \
  __syncthreads(); \
  for (int s2 = tid; s2 < S; s2 += 256) oidx[b*S + s2] = oibuf[s2];

static __device__ __forceinline__ void fps16_body(const float* __restrict__ pts,
    int S, int* __restrict__ oidx, int b, char* smraw)
{
  F2_BODY(2048, REP16, REP16D)
}

static __device__ __forceinline__ void fps4_body(const float* __restrict__ pts,
    int S, int* __restrict__ oidx, int b, char* smraw)
{
  F2_BODY(512, REP4, REP4D)
}

// ---------------- fused launch 1: fps0 (32) | knn1_part (2048) | proj (256) --------
__global__ __launch_bounds__(256) void fused1_kernel(const float* __restrict__ x,
    const float* __restrict__ w_in, const float* __restrict__ b_in,
    float* __restrict__ f0, float* __restrict__ pd1, unsigned char* __restrict__ pi1,
    int* __restrict__ fidx0)
{
  __shared__ __align__(16) char sm[4096];
  int bid = blockIdx.x;
  if (bid < 32){
    __builtin_amdgcn_s_setprio(3);
    fps16_body(x, 512, fidx0, bid, sm);   // all 256 threads enter (barrier parity)
  } else if (bid < 32+2048){
    int r = bid - 32;
    int b = r & 31; int rest = r >> 5;
    knn_part_body(x, x, 2048, 2048, 8, pd1, pi1, b, rest & 7, rest >> 3, (float4*)sm);
  } else {
    proj_body(x, w_in, b_in, f0, bid - 2080);
  }
}

// ---------------- fused launch 2: fps1 (32) | knn2_part (512) | knn3_part (128) ----
__global__ __launch_bounds__(256) void fused2_kernel(const float* __restrict__ coorq1,
    const float* __restrict__ x,
    float* __restrict__ pd2, unsigned char* __restrict__ pi2,
    float* __restrict__ pd3, unsigned char* __restrict__ pi3,
    int* __restrict__ fidx1)
{
  __shared__ __align__(16) char sm[4096];
  int bid = blockIdx.x;
  if (bid < 32){
    __builtin_amdgcn_s_setprio(3);
    fps4_body(coorq1, 128, fidx1, bid, sm);
  } else if (bid < 32+512){
    int r = bid - 32;
    int b = r & 31; int rest = r >> 5;
    knn_part_body(coorq1, x, 512, 2048, 8, pd2, pi2, b, rest & 1, rest >> 1, (float4*)sm);
  } else {
    int r = bid - 544;
    int b = r & 31; int rest = r >> 5;
    knn_part_body(coorq1, coorq1, 512, 512, 2, pd3, pi3, b, rest & 1, rest >> 1, (float4*)sm);
  }
}

// ---------------- standalone knn_part (stage 4) ----------------
__global__ __launch_bounds__(256) void knn_part_kernel(const float* __restrict__ qpts,
    const float* __restrict__ kpts, int Nq, int Nk,
    float* __restrict__ pd, unsigned char* __restrict__ pi)
{
  __shared__ __align__(16) float4 kk4[KC];
  knn_part_body(qpts, kpts, Nq, Nk, gridDim.z, pd, pi,
                blockIdx.x, blockIdx.y, blockIdx.z, kk4);
}

// ---------------- kNN pass 2: merge per-chunk sorted candidate lists ----------------
__global__ __launch_bounds__(256) void knn_merge_kernel(const float* __restrict__ pd,
    const unsigned char* __restrict__ pi, int Nq, int nkc, int* __restrict__ oidx)
{
  int gid = blockIdx.x*256 + threadIdx.x;
  if (gid >= BB*Nq) return;               // gid = b*Nq + q
  float th[KNB]; int ti[KNB];
  #pragma unroll
  for (int i=0;i<KNB;i++){ th[i] = __builtin_inff(); ti[i] = 0; }
  size_t base = (size_t)gid*nkc*KNB;
  for (int kc=0;kc<nkc;kc++){
    size_t cb = base + (size_t)kc*KNB;
    for (int i=0;i<KNB;i++){
      float d = pd[cb+i];
      if (d >= th[KNB-1]) break;           // chunk list sorted ascending
      int j = kc*KC + (int)pi[cb+i];
      th[KNB-1] = d; ti[KNB-1] = j;
      #pragma unroll
      for (int m=KNB-1;m>0;--m){
        if (th[m] < th[m-1]){
          float tv=th[m]; th[m]=th[m-1]; th[m-1]=tv;
          int tj=ti[m]; ti[m]=ti[m-1]; ti[m-1]=tj;
        }
      }
    }
  }
  #pragma unroll
  for (int i=0;i<KNB;i++) oidx[gid*KNB + i] = ti[i];
}

// ---------------- per-point GEMV ----------------
template<int C, int O, bool DIFF>
__global__ __launch_bounds__(256) void gemv_kernel(const float* __restrict__ fin,
    const float* __restrict__ W, float* __restrict__ out, int Npts)
{
  constexpr int NT = O/8;
  constexpr int LNT = ilog2c(NT);
  int gid = blockIdx.x*256 + threadIdx.x;
  if (gid >= BB*Npts*NT) return;
  int tile = gid & (NT-1);
  int pn = gid >> LNT;
  const float* frow = fin + pn*C;
  float f[C];
  #pragma unroll
  for (int c=0;c<C;c++) f[c] = frow[c];
  float acc[8];
  const float* wbase = W + (tile*8)*(2*C);
  #pragma unroll
  for (int oo=0;oo<8;oo++){
    const float* wrow = wbase + oo*(2*C);
    float a = 0.f;
    #pragma unroll
    for (int c=0;c<C;c++){
      float wv = DIFF ? __fsub_rn(wrow[C+c], wrow[c]) : wrow[c];
      a = __fmaf_rn(wv, f[c], a);
    }
    acc[oo] = a;
  }
  float* orow = out + pn*O + tile*8;
  #pragma unroll
  for (int oo=0;oo<8;oo++) orow[oo] = acc[oo];
}

// ---------------- GN stats pass ----------------
template<int O>
__global__ __launch_bounds__(256) void stats_kernel(const float* __restrict__ A,
    const float* __restrict__ Bq, const int* __restrict__ idx, int Nq, int Nk,
    double* __restrict__ part)
{
  constexpr int O4 = O/4;
  constexpr int LO4 = ilog2c(O4);
  int b = blockIdx.x, g = blockIdx.y, split = blockIdx.z;
  int nsplit = gridDim.z;
  int qlen = Nq / nsplit;
  int q0 = split * qlen;
  int tid = threadIdx.x;
  int total = qlen * KNB * O4;
  double s1 = 0.0, s2 = 0.0;
  for (int s = tid; s < total; s += 256){
    int oin = s & (O4-1);
    int rest = s >> LO4;
    int kk = rest & (KNB-1);
    int q = q0 + (rest >> 4);
    int j = idx[(b*Nq+q)*KNB + kk];
    float y = A[(b*Nk+j)*O + g*O4 + oin] + Bq[(b*Nq+q)*O + g*O4 + oin];
    s1 += (double)y;
    s2 += (double)y * (double)y;
  }
  #pragma unroll
  for (int m=32;m>0;m>>=1){ s1 += __shfl_down(s1,m); s2 += __shfl_down(s2,m); }
  __shared__ double sh1[4], sh2[4];
  int lane = tid & 63, w = tid >> 6;
  if (lane == 0){ sh1[w]=s1; sh2[w]=s2; }
  __syncthreads();
  if (tid == 0){
    double t1 = (sh1[0]+sh1[1])+(sh1[2]+sh1[3]);
    double t2 = (sh2[0]+sh2[1])+(sh2[2]+sh2[3]);
    int pi = (b*4+g)*nsplit + split;
    part[pi*2] = t1; part[pi*2+1] = t2;
  }
}

__global__ __launch_bounds__(128) void statsred_kernel(const double* __restrict__ part,
    int nsplit, double cnt, float* __restrict__ stats)
{
  int t = threadIdx.x;
  if (t >= BB*4) return;
  double s1=0.0, s2=0.0;
  for (int i=0;i<nsplit;i++){ s1 += part[(t*nsplit+i)*2]; s2 += part[(t*nsplit+i)*2+1]; }
  double mean = s1/cnt;
  double var = s2/cnt - mean*mean;
  double rstd = 1.0 / sqrt(var + 1e-5);
  stats[t*2] = (float)mean;
  stats[t*2+1] = (float)rstd;
}

// ---------------- final pass ----------------
template<int O>
__global__ __launch_bounds__(256) void final_kernel(const float* __restrict__ A,
    const float* __restrict__ Bq, const int* __restrict__ idx,
    const float* __restrict__ stats, const float* __restrict__ gamma,
    const float* __restrict__ beta, float* __restrict__ fout, int Nq, int Nk)
{
  constexpr int LO = ilog2c(O);
  constexpr int LO4 = ilog2c(O/4);
  int b = blockIdx.y;
  int t = blockIdx.x*256 + threadIdx.x;
  if (t >= Nq*O) return;
  int o = t & (O-1);
  int q = t >> LO;
  int g = o >> LO4;
  float mu   = stats[(b*4+g)*2];
  float rstd = stats[(b*4+g)*2+1];
  float gam = gamma[o], bet = beta[o];
  float bq = Bq[(b*Nq+q)*O + o];
  const int* ip = idx + (b*Nq+q)*KNB;
  float m = -__builtin_inff();
  #pragma unroll
  for (int kk=0;kk<KNB;kk++){
    int j = ip[kk];
    float y = A[(b*Nk+j)*O + o] + bq;
    float yn = __fmul_rn(__fsub_rn(y, mu), rstd);
    float yv = __fadd_rn(__fmul_rn(yn, gam), bet);
    float l = yv >= 0.f ? yv : 0.2f*yv;
    m = fmaxf(m, l);
  }
  fout[(b*Nq+q)*O + o] = m;
}

// ---------------- gathers --------------------------------
template<int C>
__global__ __launch_bounds__(256) void gather_kernel(const int* __restrict__ fidx,
    const float* __restrict__ pts, const float* __restrict__ fin,
    float* __restrict__ cq, float* __restrict__ fq, int Nin, int Nout)
{
  int gid = blockIdx.x*256 + threadIdx.x;
  if (gid >= BB*Nout) return;
  int b = gid / Nout;
  int i = gid - b*Nout;
  int src = fidx[b*Nout + i];
  #pragma unroll
  for (int c=0;c<3;c++) cq[gid*3+c] = pts[(b*Nin+src)*3+c];
  #pragma unroll
  for (int c=0;c<C;c++) fq[gid*C+c] = fin[(b*Nin+src)*C+c];
}

__global__ __launch_bounds__(256) void gatherc_kernel(const int* __restrict__ fidx,
    const float* __restrict__ pts, float* __restrict__ cq, int Nin, int Nout)
{
  int gid = blockIdx.x*256 + threadIdx.x;
  if (gid >= BB*Nout) return;
  int b = gid / Nout;
  int i = gid - b*Nout;
  int src = fidx[b*Nout + i];
  #pragma unroll
  for (int c=0;c<3;c++) cq[gid*3+c] = pts[(b*Nin+src)*3+c];
}

template<int C>
__global__ __launch_bounds__(256) void gatherf_kernel(const int* __restrict__ fidx,
    const float* __restrict__ fin, float* __restrict__ fq, int Nin, int Nout)
{
  int gid = blockIdx.x*256 + threadIdx.x;
  if (gid >= BB*Nout) return;
  int b = gid / Nout;
  int i = gid - b*Nout;
  int src = fidx[b*Nout + i];
  #pragma unroll
  for (int c=0;c<C;c++) fq[gid*C+c] = fin[(b*Nin+src)*C+c];
}

extern "C" void kernel_launch(void* const* d_in, const int* in_sizes, int n_in,
                              void* d_out, int out_size, void* d_ws, size_t ws_size,
                              hipStream_t stream)
{
  (void)in_sizes; (void)n_in; (void)out_size; (void)ws_size;
  const float* x    = (const float*)d_in[0];
  const float* w_in = (const float*)d_in[1];
  const float* b_in = (const float*)d_in[2];
  const float* w1 = (const float*)d_in[3];
  const float* g1 = (const float*)d_in[4];
  const float* be1= (const float*)d_in[5];
  const float* w2 = (const float*)d_in[6];
  const float* g2 = (const float*)d_in[7];
  const float* be2= (const float*)d_in[8];
  const float* w3 = (const float*)d_in[9];
  const float* g3 = (const float*)d_in[10];
  const float* be3= (const float*)d_in[11];
  const float* w4 = (const float*)d_in[12];
  const float* g4 = (const float*)d_in[13];
  const float* be4= (const float*)d_in[14];

  float* out = (float*)d_out;
  float* coor_out = out;                    // (32,128,3)
  float* f_out = out + BB*128*3;            // (32,128,256)

  char* ws = (char*)d_ws;
  size_t off = 0;
  auto alloc = [&](size_t bytes)->void*{ void* p = ws + off; off += (bytes + 255) & ~(size_t)255; return p; };

  // ---- persistent buffers (~41.5 MB) ----
  float* f0     = (float*)alloc((size_t)BB*2048*8*4);
  int*   idx1   = (int*)  alloc((size_t)BB*2048*16*4);
  float* f1     = (float*)alloc((size_t)BB*2048*32*4);
  double* part  = (double*)alloc((size_t)BB*4*8*2*8);
  float* statsv = (float*)alloc((size_t)BB*4*2*4);
  int*   fidx0  = (int*)  alloc((size_t)BB*512*4);
  float* coorq1 = (float*)alloc((size_t)BB*512*3*4);
  float* fq1    = (float*)alloc((size_t)BB*512*32*4);
  int*   idx2   = (int*)  alloc((size_t)BB*512*16*4);
  float* f2     = (float*)alloc((size_t)BB*512*64*4);
  int*   idx3   = (int*)  alloc((size_t)BB*512*16*4);
  float* f3     = (float*)alloc((size_t)BB*512*64*4);
  int*   fidx1  = (int*)  alloc((size_t)BB*128*4);
  float* fq2    = (float*)alloc((size_t)BB*128*64*4);
  int*   idx4   = (int*)  alloc((size_t)BB*128*16*4);
  // stage 2/3/4 kNN partials (persistent so they can coexist with fused launches)
  float* pd2          = (float*)alloc((size_t)BB*512*8*KNB*4);   // 8 MB
  unsigned char* pi2  = (unsigned char*)alloc((size_t)BB*512*8*KNB); // 2 MB
  float* pd3          = (float*)alloc((size_t)BB*512*2*KNB*4);   // 2 MB
  unsigned char* pi3  = (unsigned char*)alloc((size_t)BB*512*2*KNB); // 0.5 MB
  float* pd4          = (float*)alloc((size_t)BB*128*2*KNB*4);   // 0.5 MB
  unsigned char* pi4  = (unsigned char*)alloc((size_t)BB*128*2*KNB); // 0.125 MB

  // ---- union scratch region (48 MB): stage-1 kNN partials alias A/B buffers.
  char* U = (char*)alloc((size_t)48<<20);
  float* pd1         = (float*)U;                              // 32 MiB
  unsigned char* pi1 = (unsigned char*)(U + ((size_t)34<<20)); // 8 MiB
  float* A  = (float*)U;                                       // max 16 MiB
  float* Bq = (float*)(U + ((size_t)20<<20));                  // max 4 MiB

  auto cdiv = [](int a, int b){ return (a+b-1)/b; };

  // ==== F1: fps0 | knn1_part | proj (all depend only on x) ====
  fused1_kernel<<<2336,256,0,stream>>>(x, w_in, b_in, f0, pd1, pi1, fidx0);

  // ---- stage 1 compute ----
  knn_merge_kernel<<<cdiv(BB*2048,256),256,0,stream>>>(pd1, pi1, 2048, 8, idx1);
  gemv_kernel<8,32,false><<<cdiv(BB*2048*4,256),256,0,stream>>>(f0, w1, A, 2048);
  gemv_kernel<8,32,true ><<<cdiv(BB*2048*4,256),256,0,stream>>>(f0, w1, Bq, 2048);
  stats_kernel<32><<<dim3(BB,4,8),256,0,stream>>>(A, Bq, idx1, 2048, 2048, part);
  statsred_kernel<<<1,128,0,stream>>>(part, 8, 8.0*2048*16, statsv);
  final_kernel<32><<<dim3(cdiv(2048*32,256),BB),256,0,stream>>>(A, Bq, idx1, statsv, g1, be1, f1, 2048, 2048);

  // ---- gather at fps0 indices ----
  gather_kernel<32><<<cdiv(BB*512,256),256,0,stream>>>(fidx0, x, f1, coorq1, fq1, 2048, 512);

  // ==== F2: fps1 | knn2_part | knn3_part (all depend only on coorq1/x) ====
  fused2_kernel<<<672,256,0,stream>>>(coorq1, x, pd2, pi2, pd3, pi3, fidx1);

  knn_merge_kernel<<<cdiv(BB*512,256),256,0,stream>>>(pd2, pi2, 512, 8, idx2);
  knn_merge_kernel<<<cdiv(BB*512,256),256,0,stream>>>(pd3, pi3, 512, 2, idx3);

  // ---- stage-4 kNN early (needs only fidx1 + coorq1) ----
  gatherc_kernel<<<cdiv(BB*128,256),256,0,stream>>>(fidx1, coorq1, coor_out, 512, 128);
  knn_part_kernel<<<dim3(BB,1,2),256,0,stream>>>(coor_out, coorq1, 128, 512, pd4, pi4);
  knn_merge_kernel<<<cdiv(BB*128,256),256,0,stream>>>(pd4, pi4, 128, 2, idx4);

  // ---- stage 2 compute ----
  gemv_kernel<32,64,false><<<cdiv(BB*2048*8,256),256,0,stream>>>(f1, w2, A, 2048);
  gemv_kernel<32,64,true ><<<cdiv(BB*512*8,256),256,0,stream>>>(fq1, w2, Bq, 512);
  stats_kernel<64><<<dim3(BB,4,8),256,0,stream>>>(A, Bq, idx2, 512, 2048, part);
  statsred_kernel<<<1,128,0,stream>>>(part, 8, 16.0*512*16, statsv);
  final_kernel<64><<<dim3(cdiv(512*64,256),BB),256,0,stream>>>(A, Bq, idx2, statsv, g2, be2, f2, 512, 2048);

  // ---- stage 3 compute ----
  gemv_kernel<64,64,false><<<cdiv(BB*512*8,256),256,0,stream>>>(f2, w3, A, 512);
  gemv_kernel<64,64,true ><<<cdiv(BB*512*8,256),256,0,stream>>>(f2, w3, Bq, 512);
  stats_kernel<64><<<dim3(BB,4,8),256,0,stream>>>(A, Bq, idx3, 512, 512, part);
  statsred_kernel<<<1,128,0,stream>>>(part, 8, 16.0*512*16, statsv);
  final_kernel<64><<<dim3(cdiv(512*64,256),BB),256,0,stream>>>(A, Bq, idx3, statsv, g3, be3, f3, 512, 512);

  // ---- stage 4 compute ----
  gatherf_kernel<64><<<cdiv(BB*128,256),256,0,stream>>>(fidx1, f3, fq2, 512, 128);
  gemv_kernel<64,256,false><<<cdiv(BB*512*32,256),256,0,stream>>>(f3, w4, A, 512);
  gemv_kernel<64,256,true ><<<cdiv(BB*128*32,256),256,0,stream>>>(fq2, w4, Bq, 128);
  stats_kernel<256><<<dim3(BB,4,8),256,0,stream>>>(A, Bq, idx4, 128, 512, part);
  statsred_kernel<<<1,128,0,stream>>>(part, 8, 64.0*128*16, statsv);
  final_kernel<256><<<dim3(cdiv(128*256,256),BB),256,0,stream>>>(A, Bq, idx4, statsv, g4, be4, f_out, 128, 512);
}

// Round 12
// 1364.419 us; speedup vs baseline: 1.0831x; 1.0831x over previous
//
#include <hip/hip_runtime.h>

#define BB 32
#define NPTS0 2048
#define KNB 16
#define KC 256   // key-chunk size for two-pass kNN

constexpr int ilog2c(int n){ int l=0; while(n>1){ n>>=1; ++l; } return l; }

static __device__ __forceinline__ float sq3(float a, float b, float c){
  return __fadd_rn(__fadd_rn(__fmul_rn(a,a),__fmul_rn(b,b)),__fmul_rn(c,c));
}

// DPP helpers: templated so dpp_ctrl/row_mask are integer constant expressions.
template<int CTRL, int RM>
static __device__ __forceinline__ float dpp_maxf(float v){
  int s = __builtin_amdgcn_update_dpp(__float_as_int(v), __float_as_int(v), CTRL, RM, 0xF, false);
  return fmaxf(v, __int_as_float(s));
}
template<int CTRL, int RM>
static __device__ __forceinline__ unsigned dpp_minu(unsigned v){
  unsigned s = (unsigned)__builtin_amdgcn_update_dpp((int)v, (int)v, CTRL, RM, 0xF, false);
  return s < v ? s : v;
}

// ---------------- proj body ----------------
static __device__ __forceinline__ void proj_body(const float* __restrict__ x,
    const float* __restrict__ w, const float* __restrict__ bias, float* __restrict__ f0,
    int blk)
{
  int gid = blk*256 + threadIdx.x;
  if (gid >= BB*NPTS0) return;
  float x0 = x[gid*3+0], x1 = x[gid*3+1], x2 = x[gid*3+2];
  #pragma unroll
  for (int o = 0; o < 8; ++o){
    float acc = __fmul_rn(w[o*3+0], x0);
    acc = __fmaf_rn(w[o*3+1], x1, acc);
    acc = __fmaf_rn(w[o*3+2], x2, acc);
    f0[gid*8+o] = __fadd_rn(acc, bias[o]);
  }
}

// ---------------- kNN pass 1 body: NAMED-SCALAR top-16 (registers, no allocas) ------
#define KDECL(I) float th##I = __builtin_inff(); int ti##I = 0;
#define KINS(I,J) if (th##I < th##J){ float tv=th##I; th##I=th##J; th##J=tv; \
                                      int tj=ti##I; ti##I=ti##J; ti##J=tj; }
#define KST(I) pd[base+I] = th##I; pi[base+I] = (unsigned char)ti##I;

static __device__ __forceinline__ void knn_part_body(const float* __restrict__ qpts,
    const float* __restrict__ kpts, int Nq, int Nk, int nkc,
    float* __restrict__ pd, unsigned char* __restrict__ pi,
    int b, int qcb, int kc, float4* kk4)
{
  int tid = threadIdx.x;
  {
    int j = kc*KC + tid;                 // Nk is always a multiple of 256
    float a = kpts[(b*Nk+j)*3+0];
    float c = kpts[(b*Nk+j)*3+1];
    float d = kpts[(b*Nk+j)*3+2];
    kk4[tid] = make_float4(a, c, d, sq3(a,c,d));
  }
  __syncthreads();
  int q = qcb*256 + tid;
  if (q >= Nq) return;
  float qx = qpts[(b*Nq+q)*3+0], qy = qpts[(b*Nq+q)*3+1], qz = qpts[(b*Nq+q)*3+2];
  float qq = sq3(qx,qy,qz);
  KDECL(0) KDECL(1) KDECL(2) KDECL(3) KDECL(4) KDECL(5) KDECL(6) KDECL(7)
  KDECL(8) KDECL(9) KDECL(10) KDECL(11) KDECL(12) KDECL(13) KDECL(14) KDECL(15)
  for (int j=0;j<KC;j++){
    float4 k4 = kk4[j];
    float dot = __fmul_rn(qx,k4.x);
    dot = __fmaf_rn(qy,k4.y,dot);
    dot = __fmaf_rn(qz,k4.z,dot);
    float d = __fadd_rn(__fsub_rn(qq, __fmul_rn(2.0f,dot)), k4.w);
    if (d < th15){                        // strict <: equal dist keeps earlier index
      th15 = d; ti15 = j;
      KINS(15,14) KINS(14,13) KINS(13,12) KINS(12,11) KINS(11,10) KINS(10,9)
      KINS(9,8) KINS(8,7) KINS(7,6) KINS(6,5) KINS(5,4) KINS(4,3) KINS(3,2)
      KINS(2,1) KINS(1,0)
    }
  }
  size_t base = ((size_t)(b*Nq+q)*nkc + kc)*KNB;
  KST(0) KST(1) KST(2) KST(3) KST(4) KST(5) KST(6) KST(7)
  KST(8) KST(9) KST(10) KST(11) KST(12) KST(13) KST(14) KST(15)
}

// ---------------- FPS bodies: 4-wave (R8-proven) + LDS-buffered output -------------
// Winner indices go to LDS (oibuf) and are dumped after the loop, so the in-loop
// __syncthreads waits on lgkm only (no global-store vmcnt(0) drain per iteration).
// Selection semantics identical to jnp.argmax over exact f32 distances.
#define FPS_LOAD(T) float px##T, py##T, pz##T, d##T; { int i_=T*256+tid; \
  px##T=P[i_*3+0]; py##T=P[i_*3+1]; pz##T=P[i_*3+2]; \
  float dx_=__fsub_rn(px##T,c0x), dy_=__fsub_rn(py##T,c0y), dz_=__fsub_rn(pz##T,c0z); \
  d##T=sq3(dx_,dy_,dz_); bm=fmaxf(bm,d##T); }
#define FPS_MATCH(T) if (d##T == m_w) ci = (unsigned)(T*256 + tid);
#define FPS_OWN(T) if ((idx_w>>8) == T##u){ cx=px##T; cy=py##T; cz=pz##T; }
#define FPS_UPD(T) { float dx_=__fsub_rn(px##T,sx), dy_=__fsub_rn(py##T,sy), dz_=__fsub_rn(pz##T,sz); \
  float nd_=sq3(dx_,dy_,dz_); d##T=fminf(d##T,nd_); nbm=fmaxf(nbm,d##T); }

#define FPS_REDUCE_AND_PICK \
    float v = bm; \
    v = dpp_maxf<0x111, 0xF>(v); \
    v = dpp_maxf<0x112, 0xF>(v); \
    v = dpp_maxf<0x114, 0xF>(v); \
    v = dpp_maxf<0x118, 0xF>(v); \
    v = dpp_maxf<0x142, 0xA>(v); \
    v = dpp_maxf<0x143, 0xC>(v); \
    float m_w = __int_as_float(__builtin_amdgcn_readlane(__float_as_int(v), 63)); \
    unsigned ci = 0xFFFFFFFFu;

#define FPS_MIN_AND_MERGE \
    ci = dpp_minu<0x111, 0xF>(ci); \
    ci = dpp_minu<0x112, 0xF>(ci); \
    ci = dpp_minu<0x114, 0xF>(ci); \
    ci = dpp_minu<0x118, 0xF>(ci); \
    ci = dpp_minu<0x142, 0xA>(ci); \
    ci = dpp_minu<0x143, 0xC>(ci); \
    unsigned idx_w = (unsigned)__builtin_amdgcn_readlane((int)ci, 63); \
    int par = s & 1;

#define FPS_CROSSWAVE \
    __syncthreads(); \
    float4 q0 = *(const float4*)&swp[par][0][0]; float z0 = swp[par][0][4]; \
    float4 q1 = *(const float4*)&swp[par][1][0]; float z1 = swp[par][1][4]; \
    float4 q2 = *(const float4*)&swp[par][2][0]; float z2 = swp[par][2][4]; \
    float4 q3 = *(const float4*)&swp[par][3][0]; float z3 = swp[par][3][4]; \
    float mm = q0.x; unsigned mi = __float_as_uint(q0.y); \
    float sx = q0.z, sy = q0.w, sz = z0; \
    if (q1.x > mm || (q1.x == mm && __float_as_uint(q1.y) < mi)){ \
      mm = q1.x; mi = __float_as_uint(q1.y); sx = q1.z; sy = q1.w; sz = z1; } \
    if (q2.x > mm || (q2.x == mm && __float_as_uint(q2.y) < mi)){ \
      mm = q2.x; mi = __float_as_uint(q2.y); sx = q2.z; sy = q2.w; sz = z2; } \
    if (q3.x > mm || (q3.x == mm && __float_as_uint(q3.y) < mi)){ \
      mm = q3.x; mi = __float_as_uint(q3.y); sx = q3.z; sy = q3.w; sz = z3; } \
    if (tid == 0) oibuf[s] = (int)mi;

static __device__ __forceinline__ void fps8_body(const float* __restrict__ pts,
    int S, int* __restrict__ oidx, int b, char* smraw)
{
  float (*swp)[4][8] = reinterpret_cast<float(*)[4][8]>(smraw);  // [2][4][8] = 256B
  int* oibuf = reinterpret_cast<int*>(smraw + 256);              // S*4 bytes
  int tid = threadIdx.x, wid = tid >> 6;
  const float* P = pts + (size_t)b*2048*3;
  float c0x = P[0], c0y = P[1], c0z = P[2];
  float bm = -1.0f;
  FPS_LOAD(0) FPS_LOAD(1) FPS_LOAD(2) FPS_LOAD(3)
  FPS_LOAD(4) FPS_LOAD(5) FPS_LOAD(6) FPS_LOAD(7)
  if (tid == 0) oibuf[0] = 0;
  for (int s=1; s<S; ++s){
    FPS_REDUCE_AND_PICK
    FPS_MATCH(7) FPS_MATCH(6) FPS_MATCH(5) FPS_MATCH(4)
    FPS_MATCH(3) FPS_MATCH(2) FPS_MATCH(1) FPS_MATCH(0)
    FPS_MIN_AND_MERGE
    if (tid == (int)(idx_w & 255u)){       // each wave's winner lane writes its slot
      float cx = px0, cy = py0, cz = pz0;
      FPS_OWN(1) FPS_OWN(2) FPS_OWN(3) FPS_OWN(4) FPS_OWN(5) FPS_OWN(6) FPS_OWN(7)
      float4* wp = (float4*)&swp[par][wid][0];
      *wp = make_float4(m_w, __uint_as_float(idx_w), cx, cy);
      swp[par][wid][4] = cz;
    }
    FPS_CROSSWAVE
    float nbm = -1.0f;
    FPS_UPD(0) FPS_UPD(1) FPS_UPD(2) FPS_UPD(3)
    FPS_UPD(4) FPS_UPD(5) FPS_UPD(6) FPS_UPD(7)
    bm = nbm;
  }
  __syncthreads();
  for (int s2 = tid; s2 < S; s2 += 256) oidx[b*S + s2] = oibuf[s2];
}

static __device__ __forceinline__ void fps2_body(const float* __restrict__ pts,
    int S, int* __restrict__ oidx, int b, char* smraw)
{
  float (*swp)[4][8] = reinterpret_cast<float(*)[4][8]>(smraw);
  int* oibuf = reinterpret_cast<int*>(smraw + 256);
  int tid = threadIdx.x, wid = tid >> 6;
  const float* P = pts + (size_t)b*512*3;
  float c0x = P[0], c0y = P[1], c0z = P[2];
  float bm = -1.0f;
  FPS_LOAD(0) FPS_LOAD(1)
  if (tid == 0) oibuf[0] = 0;
  for (int s=1; s<S; ++s){
    FPS_REDUCE_AND_PICK
    FPS_MATCH(1) FPS_MATCH(0)
    FPS_MIN_AND_MERGE
    if (tid == (int)(idx_w & 255u)){
      float cx = px0, cy = py0, cz = pz0;
      FPS_OWN(1)
      float4* wp = (float4*)&swp[par][wid][0];
      *wp = make_float4(m_w, __uint_as_float(idx_w), cx, cy);
      swp[par][wid][4] = cz;
    }
    FPS_CROSSWAVE
    float nbm = -1.0f;
    FPS_UPD(0) FPS_UPD(1)
    bm = nbm;
  }
  __syncthreads();
  for (int s2 = tid; s2 < S; s2 += 256) oidx[b*S + s2] = oibuf[s2];
}

// ---------------- fused launch 1: fps0 (32) | knn1_part (2048) | proj (256) --------
__global__ __launch_bounds__(256) void fused1_kernel(const float* __restrict__ x,
    const float* __restrict__ w_in, const float* __restrict__ b_in,
    float* __restrict__ f0, float* __restrict__ pd1, unsigned char* __restrict__ pi1,
    int* __restrict__ fidx0)
{
  __shared__ __align__(16) char sm[4096];
  int bid = blockIdx.x;
  if (bid < 32){
    __builtin_amdgcn_s_setprio(3);
    fps8_body(x, 512, fidx0, bid, sm);
  } else if (bid < 32+2048){
    int r = bid - 32;
    int b = r & 31; int rest = r >> 5;
    knn_part_body(x, x, 2048, 2048, 8, pd1, pi1, b, rest & 7, rest >> 3, (float4*)sm);
  } else {
    proj_body(x, w_in, b_in, f0, bid - 2080);
  }
}

// ---------------- fused launch 2: fps1 (32) | knn2_part (512) | knn3_part (128) ----
__global__ __launch_bounds__(256) void fused2_kernel(const float* __restrict__ coorq1,
    const float* __restrict__ x,
    float* __restrict__ pd2, unsigned char* __restrict__ pi2,
    float* __restrict__ pd3, unsigned char* __restrict__ pi3,
    int* __restrict__ fidx1)
{
  __shared__ __align__(16) char sm[4096];
  int bid = blockIdx.x;
  if (bid < 32){
    __builtin_amdgcn_s_setprio(3);
    fps2_body(coorq1, 128, fidx1, bid, sm);
  } else if (bid < 32+512){
    int r = bid - 32;
    int b = r & 31; int rest = r >> 5;
    knn_part_body(coorq1, x, 512, 2048, 8, pd2, pi2, b, rest & 1, rest >> 1, (float4*)sm);
  } else {
    int r = bid - 544;
    int b = r & 31; int rest = r >> 5;
    knn_part_body(coorq1, coorq1, 512, 512, 2, pd3, pi3, b, rest & 1, rest >> 1, (float4*)sm);
  }
}

// ---------------- standalone knn_part (stage 4) ----------------
__global__ __launch_bounds__(256) void knn_part_kernel(const float* __restrict__ qpts,
    const float* __restrict__ kpts, int Nq, int Nk,
    float* __restrict__ pd, unsigned char* __restrict__ pi)
{
  __shared__ __align__(16) float4 kk4[KC];
  knn_part_body(qpts, kpts, Nq, Nk, gridDim.z, pd, pi,
                blockIdx.x, blockIdx.y, blockIdx.z, kk4);
}

// ---------------- kNN pass 2: merge per-chunk sorted candidate lists ----------------
__global__ __launch_bounds__(256) void knn_merge_kernel(const float* __restrict__ pd,
    const unsigned char* __restrict__ pi, int Nq, int nkc, int* __restrict__ oidx)
{
  int gid = blockIdx.x*256 + threadIdx.x;
  if (gid >= BB*Nq) return;               // gid = b*Nq + q
  float th[KNB]; int ti[KNB];
  #pragma unroll
  for (int i=0;i<KNB;i++){ th[i] = __builtin_inff(); ti[i] = 0; }
  size_t base = (size_t)gid*nkc*KNB;
  for (int kc=0;kc<nkc;kc++){
    size_t cb = base + (size_t)kc*KNB;
    for (int i=0;i<KNB;i++){
      float d = pd[cb+i];
      if (d >= th[KNB-1]) break;           // chunk list sorted ascending
      int j = kc*KC + (int)pi[cb+i];
      th[KNB-1] = d; ti[KNB-1] = j;
      #pragma unroll
      for (int m=KNB-1;m>0;--m){
        if (th[m] < th[m-1]){
          float tv=th[m]; th[m]=th[m-1]; th[m-1]=tv;
          int tj=ti[m]; ti[m]=ti[m-1]; ti[m-1]=tj;
        }
      }
    }
  }
  #pragma unroll
  for (int i=0;i<KNB;i++) oidx[gid*KNB + i] = ti[i];
}

// ---------------- per-point GEMV ----------------
template<int C, int O, bool DIFF>
__global__ __launch_bounds__(256) void gemv_kernel(const float* __restrict__ fin,
    const float* __restrict__ W, float* __restrict__ out, int Npts)
{
  constexpr int NT = O/8;
  constexpr int LNT = ilog2c(NT);
  int gid = blockIdx.x*256 + threadIdx.x;
  if (gid >= BB*Npts*NT) return;
  int tile = gid & (NT-1);
  int pn = gid >> LNT;
  const float* frow = fin + pn*C;
  float f[C];
  #pragma unroll
  for (int c=0;c<C;c++) f[c] = frow[c];
  float acc[8];
  const float* wbase = W + (tile*8)*(2*C);
  #pragma unroll
  for (int oo=0;oo<8;oo++){
    const float* wrow = wbase + oo*(2*C);
    float a = 0.f;
    #pragma unroll
    for (int c=0;c<C;c++){
      float wv = DIFF ? __fsub_rn(wrow[C+c], wrow[c]) : wrow[c];
      a = __fmaf_rn(wv, f[c], a);
    }
    acc[oo] = a;
  }
  float* orow = out + pn*O + tile*8;
  #pragma unroll
  for (int oo=0;oo<8;oo++) orow[oo] = acc[oo];
}

// ---------------- GN stats pass v2: one thread per (q,kk) pair ----------------
// idx loaded once per pair; A/B rows read as coalesced float4; per-group chunk
// sums in f32 (<=64 elements, |y| small) folded into f64 accumulators.
// grid (BB, nsplit), block 256. part layout unchanged: pi=(b*4+g)*nsplit+split.
template<int O>
__global__ __launch_bounds__(256) void stats2_kernel(const float* __restrict__ A,
    const float* __restrict__ Bq, const int* __restrict__ idx, int Nq, int Nk,
    double* __restrict__ part)
{
  constexpr int O4 = O/4;
  int b = blockIdx.x, split = blockIdx.y, nsplit = gridDim.y;
  int qlen = Nq / nsplit, q0 = split*qlen;
  int tid = threadIdx.x;
  int pairs = qlen * KNB;
  double s1[4] = {0.0,0.0,0.0,0.0};
  double s2[4] = {0.0,0.0,0.0,0.0};
  for (int p = tid; p < pairs; p += 256){
    int q = q0 + (p >> 4);
    int kk = p & 15;
    int j = idx[(b*Nq+q)*KNB + kk];
    const float* arow = A + (size_t)(b*Nk+j)*O;
    const float* brow = Bq + (size_t)(b*Nq+q)*O;
    #pragma unroll
    for (int g=0; g<4; ++g){
      float cs1 = 0.f, cs2 = 0.f;
      #pragma unroll
      for (int c=0; c<O4; c+=4){
        float4 a4 = *(const float4*)(arow + g*O4 + c);
        float4 b4 = *(const float4*)(brow + g*O4 + c);
        float y0 = a4.x+b4.x, y1 = a4.y+b4.y, y2 = a4.z+b4.z, y3 = a4.w+b4.w;
        cs1 += ((y0+y1)+(y2+y3));
        cs2 = fmaf(y0,y0,cs2); cs2 = fmaf(y1,y1,cs2);
        cs2 = fmaf(y2,y2,cs2); cs2 = fmaf(y3,y3,cs2);
      }
      s1[g] += (double)cs1;
      s2[g] += (double)cs2;
    }
  }
  // wave reduce (8 doubles) then cross-wave via LDS
  #pragma unroll
  for (int m=32;m>0;m>>=1){
    #pragma unroll
    for (int g=0; g<4; ++g){
      s1[g] += __shfl_down(s1[g], m);
      s2[g] += __shfl_down(s2[g], m);
    }
  }
  __shared__ double sh[4][8];
  int lane = tid & 63, w = tid >> 6;
  if (lane == 0){
    #pragma unroll
    for (int g=0; g<4; ++g){ sh[w][g*2] = s1[g]; sh[w][g*2+1] = s2[g]; }
  }
  __syncthreads();
  if (tid == 0){
    #pragma unroll
    for (int g=0; g<4; ++g){
      double t1 = (sh[0][g*2]+sh[1][g*2]) + (sh[2][g*2]+sh[3][g*2]);
      double t2 = (sh[0][g*2+1]+sh[1][g*2+1]) + (sh[2][g*2+1]+sh[3][g*2+1]);
      int pi = (b*4+g)*nsplit + split;
      part[pi*2] = t1; part[pi*2+1] = t2;
    }
  }
}

__global__ __launch_bounds__(128) void statsred_kernel(const double* __restrict__ part,
    int nsplit, double cnt, float* __restrict__ stats)
{
  int t = threadIdx.x;
  if (t >= BB*4) return;
  double s1=0.0, s2=0.0;
  for (int i=0;i<nsplit;i++){ s1 += part[(t*nsplit+i)*2]; s2 += part[(t*nsplit+i)*2+1]; }
  double mean = s1/cnt;
  double var = s2/cnt - mean*mean;
  double rstd = 1.0 / sqrt(var + 1e-5);
  stats[t*2] = (float)mean;
  stats[t*2+1] = (float)rstd;
}

// ---------------- final pass ----------------
template<int O>
__global__ __launch_bounds__(256) void final_kernel(const float* __restrict__ A,
    const float* __restrict__ Bq, const int* __restrict__ idx,
    const float* __restrict__ stats, const float* __restrict__ gamma,
    const float* __restrict__ beta, float* __restrict__ fout, int Nq, int Nk)
{
  constexpr int LO = ilog2c(O);
  constexpr int LO4 = ilog2c(O/4);
  int b = blockIdx.y;
  int t = blockIdx.x*256 + threadIdx.x;
  if (t >= Nq*O) return;
  int o = t & (O-1);
  int q = t >> LO;
  int g = o >> LO4;
  float mu   = stats[(b*4+g)*2];
  float rstd = stats[(b*4+g)*2+1];
  float gam = gamma[o], bet = beta[o];
  float bq = Bq[(b*Nq+q)*O + o];
  const int* ip = idx + (b*Nq+q)*KNB;
  float m = -__builtin_inff();
  #pragma unroll
  for (int kk=0;kk<KNB;kk++){
    int j = ip[kk];
    float y = A[(b*Nk+j)*O + o] + bq;
    float yn = __fmul_rn(__fsub_rn(y, mu), rstd);
    float yv = __fadd_rn(__fmul_rn(yn, gam), bet);
    float l = yv >= 0.f ? yv : 0.2f*yv;
    m = fmaxf(m, l);
  }
  fout[(b*Nq+q)*O + o] = m;
}

// ---------------- gathers --------------------------------
template<int C>
__global__ __launch_bounds__(256) void gather_kernel(const int* __restrict__ fidx,
    const float* __restrict__ pts, const float* __restrict__ fin,
    float* __restrict__ cq, float* __restrict__ fq, int Nin, int Nout)
{
  int gid = blockIdx.x*256 + threadIdx.x;
  if (gid >= BB*Nout) return;
  int b = gid / Nout;
  int i = gid - b*Nout;
  int src = fidx[b*Nout + i];
  #pragma unroll
  for (int c=0;c<3;c++) cq[gid*3+c] = pts[(b*Nin+src)*3+c];
  #pragma unroll
  for (int c=0;c<C;c++) fq[gid*C+c] = fin[(b*Nin+src)*C+c];
}

__global__ __launch_bounds__(256) void gatherc_kernel(const int* __restrict__ fidx,
    const float* __restrict__ pts, float* __restrict__ cq, int Nin, int Nout)
{
  int gid = blockIdx.x*256 + threadIdx.x;
  if (gid >= BB*Nout) return;
  int b = gid / Nout;
  int i = gid - b*Nout;
  int src = fidx[b*Nout + i];
  #pragma unroll
  for (int c=0;c<3;c++) cq[gid*3+c] = pts[(b*Nin+src)*3+c];
}

template<int C>
__global__ __launch_bounds__(256) void gatherf_kernel(const int* __restrict__ fidx,
    const float* __restrict__ fin, float* __restrict__ fq, int Nin, int Nout)
{
  int gid = blockIdx.x*256 + threadIdx.x;
  if (gid >= BB*Nout) return;
  int b = gid / Nout;
  int i = gid - b*Nout;
  int src = fidx[b*Nout + i];
  #pragma unroll
  for (int c=0;c<C;c++) fq[gid*C+c] = fin[(b*Nin+src)*C+c];
}

extern "C" void kernel_launch(void* const* d_in, const int* in_sizes, int n_in,
                              void* d_out, int out_size, void* d_ws, size_t ws_size,
                              hipStream_t stream)
{
  (void)in_sizes; (void)n_in; (void)out_size; (void)ws_size;
  const float* x    = (const float*)d_in[0];
  const float* w_in = (const float*)d_in[1];
  const float* b_in = (const float*)d_in[2];
  const float* w1 = (const float*)d_in[3];
  const float* g1 = (const float*)d_in[4];
  const float* be1= (const float*)d_in[5];
  const float* w2 = (const float*)d_in[6];
  const float* g2 = (const float*)d_in[7];
  const float* be2= (const float*)d_in[8];
  const float* w3 = (const float*)d_in[9];
  const float* g3 = (const float*)d_in[10];
  const float* be3= (const float*)d_in[11];
  const float* w4 = (const float*)d_in[12];
  const float* g4 = (const float*)d_in[13];
  const float* be4= (const float*)d_in[14];

  float* out = (float*)d_out;
  float* coor_out = out;                    // (32,128,3)
  float* f_out = out + BB*128*3;            // (32,128,256)

  char* ws = (char*)d_ws;
  size_t off = 0;
  auto alloc = [&](size_t bytes)->void*{ void* p = ws + off; off += (bytes + 255) & ~(size_t)255; return p; };

  // ---- persistent buffers (~41.5 MB) ----
  float* f0     = (float*)alloc((size_t)BB*2048*8*4);
  int*   idx1   = (int*)  alloc((size_t)BB*2048*16*4);
  float* f1     = (float*)alloc((size_t)BB*2048*32*4);
  double* part  = (double*)alloc((size_t)BB*4*8*2*8);
  float* statsv = (float*)alloc((size_t)BB*4*2*4);
  int*   fidx0  = (int*)  alloc((size_t)BB*512*4);
  float* coorq1 = (float*)alloc((size_t)BB*512*3*4);
  float* fq1    = (float*)alloc((size_t)BB*512*32*4);
  int*   idx2   = (int*)  alloc((size_t)BB*512*16*4);
  float* f2     = (float*)alloc((size_t)BB*512*64*4);
  int*   idx3   = (int*)  alloc((size_t)BB*512*16*4);
  float* f3     = (float*)alloc((size_t)BB*512*64*4);
  int*   fidx1  = (int*)  alloc((size_t)BB*128*4);
  float* fq2    = (float*)alloc((size_t)BB*128*64*4);
  int*   idx4   = (int*)  alloc((size_t)BB*128*16*4);
  // stage 2/3/4 kNN partials (persistent so they can coexist with fused launches)
  float* pd2          = (float*)alloc((size_t)BB*512*8*KNB*4);   // 8 MB
  unsigned char* pi2  = (unsigned char*)alloc((size_t)BB*512*8*KNB); // 2 MB
  float* pd3          = (float*)alloc((size_t)BB*512*2*KNB*4);   // 2 MB
  unsigned char* pi3  = (unsigned char*)alloc((size_t)BB*512*2*KNB); // 0.5 MB
  float* pd4          = (float*)alloc((size_t)BB*128*2*KNB*4);   // 0.5 MB
  unsigned char* pi4  = (unsigned char*)alloc((size_t)BB*128*2*KNB); // 0.125 MB

  // ---- union scratch region (48 MB): stage-1 kNN partials alias A/B buffers.
  char* U = (char*)alloc((size_t)48<<20);
  float* pd1         = (float*)U;                              // 32 MiB
  unsigned char* pi1 = (unsigned char*)(U + ((size_t)34<<20)); // 8 MiB
  float* A  = (float*)U;                                       // max 16 MiB
  float* Bq = (float*)(U + ((size_t)20<<20));                  // max 4 MiB

  auto cdiv = [](int a, int b){ return (a+b-1)/b; };

  // ==== F1: fps0 | knn1_part | proj (all depend only on x) ====
  fused1_kernel<<<2336,256,0,stream>>>(x, w_in, b_in, f0, pd1, pi1, fidx0);

  // ---- stage 1 compute ----
  knn_merge_kernel<<<cdiv(BB*2048,256),256,0,stream>>>(pd1, pi1, 2048, 8, idx1);
  gemv_kernel<8,32,false><<<cdiv(BB*2048*4,256),256,0,stream>>>(f0, w1, A, 2048);
  gemv_kernel<8,32,true ><<<cdiv(BB*2048*4,256),256,0,stream>>>(f0, w1, Bq, 2048);
  stats2_kernel<32><<<dim3(BB,8),256,0,stream>>>(A, Bq, idx1, 2048, 2048, part);
  statsred_kernel<<<1,128,0,stream>>>(part, 8, 8.0*2048*16, statsv);
  final_kernel<32><<<dim3(cdiv(2048*32,256),BB),256,0,stream>>>(A, Bq, idx1, statsv, g1, be1, f1, 2048, 2048);

  // ---- gather at fps0 indices ----
  gather_kernel<32><<<cdiv(BB*512,256),256,0,stream>>>(fidx0, x, f1, coorq1, fq1, 2048, 512);

  // ==== F2: fps1 | knn2_part | knn3_part (all depend only on coorq1/x) ====
  fused2_kernel<<<672,256,0,stream>>>(coorq1, x, pd2, pi2, pd3, pi3, fidx1);

  knn_merge_kernel<<<cdiv(BB*512,256),256,0,stream>>>(pd2, pi2, 512, 8, idx2);
  knn_merge_kernel<<<cdiv(BB*512,256),256,0,stream>>>(pd3, pi3, 512, 2, idx3);

  // ---- stage-4 kNN early (needs only fidx1 + coorq1) ----
  gatherc_kernel<<<cdiv(BB*128,256),256,0,stream>>>(fidx1, coorq1, coor_out, 512, 128);
  knn_part_kernel<<<dim3(BB,1,2),256,0,stream>>>(coor_out, coorq1, 128, 512, pd4, pi4);
  knn_merge_kernel<<<cdiv(BB*128,256),256,0,stream>>>(pd4, pi4, 128, 2, idx4);

  // ---- stage 2 compute ----
  gemv_kernel<32,64,false><<<cdiv(BB*2048*8,256),256,0,stream>>>(f1, w2, A, 2048);
  gemv_kernel<32,64,true ><<<cdiv(BB*512*8,256),256,0,stream>>>(fq1, w2, Bq, 512);
  stats2_kernel<64><<<dim3(BB,8),256,0,stream>>>(A, Bq, idx2, 512, 2048, part);
  statsred_kernel<<<1,128,0,stream>>>(part, 8, 16.0*512*16, statsv);
  final_kernel<64><<<dim3(cdiv(512*64,256),BB),256,0,stream>>>(A, Bq, idx2, statsv, g2, be2, f2, 512, 2048);

  // ---- stage 3 compute ----
  gemv_kernel<64,64,false><<<cdiv(BB*512*8,256),256,0,stream>>>(f2, w3, A, 512);
  gemv_kernel<64,64,true ><<<cdiv(BB*512*8,256),256,0,stream>>>(f2, w3, Bq, 512);
  stats2_kernel<64><<<dim3(BB,8),256,0,stream>>>(A, Bq, idx3, 512, 512, part);
  statsred_kernel<<<1,128,0,stream>>>(part, 8, 16.0*512*16, statsv);
  final_kernel<64><<<dim3(cdiv(512*64,256),BB),256,0,stream>>>(A, Bq, idx3, statsv, g3, be3, f3, 512, 512);

  // ---- stage 4 compute ----
  gatherf_kernel<64><<<cdiv(BB*128,256),256,0,stream>>>(fidx1, f3, fq2, 512, 128);
  gemv_kernel<64,256,false><<<cdiv(BB*512*32,256),256,0,stream>>>(f3, w4, A, 512);
  gemv_kernel<64,256,true ><<<cdiv(BB*128*32,256),256,0,stream>>>(fq2, w4, Bq, 128);
  stats2_kernel<256><<<dim3(BB,8),256,0,stream>>>(A, Bq, idx4, 128, 512, part);
  statsred_kernel<<<1,128,0,stream>>>(part, 8, 64.0*128*16, statsv);
  final_kernel<256><<<dim3(cdiv(128*256,256),BB),256,0,stream>>>(A, Bq, idx4, statsv, g4, be4, f_out, 128, 512);
}